// Round 1
// baseline (738.544 us; speedup 1.0000x reference)
//
#include <hip/hip_runtime.h>
#include <hip/hip_bf16.h>
#include <math.h>

#define ALPHA 0.2f

// ---------------- GEMM: fts[n][h*32+o] = sum_d x[n][d] * W[h][d][o] -------------
// M = N_nodes, K = 256, Ncols = 128 (4 heads * 32)
__global__ __launch_bounds__(256) void k_gemm(const float* __restrict__ x,
                                              const float* __restrict__ W,
                                              float* __restrict__ fts, int M)
{
    __shared__ float As[16][68];   // [k][m], padded: 68*4=272 bytes/row (16B aligned)
    __shared__ float Bs[16][128];  // [k][c]

    const int m0 = blockIdx.x * 64;
    const int t  = threadIdx.x;
    const int tx = t & 31;         // col group: cols tx*4 .. tx*4+3
    const int ty = t >> 5;         // row group: rows ty*8 .. ty*8+7

    float acc[8][4];
#pragma unroll
    for (int i = 0; i < 8; i++)
#pragma unroll
        for (int j = 0; j < 4; j++) acc[i][j] = 0.f;

    for (int k0 = 0; k0 < 256; k0 += 16) {
        // load A tile: 64 rows x 16 k. thread -> row t>>2, k offset (t&3)*4
        {
            int ar = t >> 2, ak = (t & 3) * 4;
            int gr = m0 + ar;
            float4 av = make_float4(0.f, 0.f, 0.f, 0.f);
            if (gr < M) av = *(const float4*)(x + (size_t)gr * 256 + k0 + ak);
            As[ak + 0][ar] = av.x;
            As[ak + 1][ar] = av.y;
            As[ak + 2][ar] = av.z;
            As[ak + 3][ar] = av.w;
        }
        // load B tile: 16 k x 128 c.  c = h*32+o maps to W[h*8192 + k*32 + o]
#pragma unroll
        for (int p = 0; p < 2; p++) {
            int kb = (t >> 5) + p * 8;
            int c4 = (t & 31) * 4;
            int h = c4 >> 5, o = c4 & 31;
            float4 bv = *(const float4*)(W + h * 8192 + (k0 + kb) * 32 + o);
            *(float4*)&Bs[kb][c4] = bv;
        }
        __syncthreads();
#pragma unroll
        for (int k = 0; k < 16; k++) {
            float4 b4 = *(float4*)&Bs[k][tx * 4];
            float4 aA = *(float4*)&As[k][ty * 8];
            float4 aB = *(float4*)&As[k][ty * 8 + 4];
            float a[8] = {aA.x, aA.y, aA.z, aA.w, aB.x, aB.y, aB.z, aB.w};
#pragma unroll
            for (int i = 0; i < 8; i++) {
                acc[i][0] = fmaf(a[i], b4.x, acc[i][0]);
                acc[i][1] = fmaf(a[i], b4.y, acc[i][1]);
                acc[i][2] = fmaf(a[i], b4.z, acc[i][2]);
                acc[i][3] = fmaf(a[i], b4.w, acc[i][3]);
            }
        }
        __syncthreads();
    }
#pragma unroll
    for (int i = 0; i < 8; i++) {
        int r = m0 + ty * 8 + i;
        if (r < M) {
            float4 v = make_float4(acc[i][0], acc[i][1], acc[i][2], acc[i][3]);
            *(float4*)(fts + (size_t)r * 128 + tx * 4) = v;
        }
    }
}

// ---------------- f1/f2: per (node, head) dot over O=32 --------------------------
__global__ __launch_bounds__(256) void k_f12(const float* __restrict__ fts,
                                             const float* __restrict__ a1,
                                             const float* __restrict__ b1,
                                             const float* __restrict__ a2,
                                             const float* __restrict__ b2,
                                             float* __restrict__ f1,
                                             float* __restrict__ f2, int Nn)
{
    int g = blockIdx.x * 256 + threadIdx.x;
    int n = g >> 2, h = g & 3;
    if (n >= Nn) return;
    const float* row = fts + (size_t)n * 128 + h * 32;
    const float* A1 = a1 + h * 32;
    const float* A2 = a2 + h * 32;
    float s1 = 0.f, s2 = 0.f;
#pragma unroll
    for (int o = 0; o < 32; o += 4) {
        float4 v  = *(const float4*)(row + o);
        float4 u1 = *(const float4*)(A1 + o);
        float4 u2 = *(const float4*)(A2 + o);
        s1 += v.x * u1.x + v.y * u1.y + v.z * u1.z + v.w * u1.w;
        s2 += v.x * u2.x + v.y * u2.y + v.z * u2.z + v.w * u2.w;
    }
    f1[h * Nn + n] = s1 + b1[h];
    f2[h * Nn + n] = s2 + b2[h];
}

// ---------------- CSR build --------------------------------------------------------
__global__ __launch_bounds__(256) void k_hist(const int* __restrict__ erow, int* __restrict__ counts, int E)
{
    int g = blockIdx.x * 256 + threadIdx.x;
    if (g < E) atomicAdd(&counts[erow[g]], 1);
}

// scan stage A: per-block (1024 elems) exclusive scan + block sums
__global__ __launch_bounds__(256) void k_scan_a(const int* __restrict__ counts,
                                                int* __restrict__ excl,
                                                int* __restrict__ blocksums, int n)
{
    __shared__ int s[256];
    int b = blockIdx.x, t = threadIdx.x;
    int base = b * 1024 + t * 4;
    int v[4];
#pragma unroll
    for (int i = 0; i < 4; i++) v[i] = (base + i < n) ? counts[base + i] : 0;
    int tsum = v[0] + v[1] + v[2] + v[3];
    s[t] = tsum;
    __syncthreads();
    for (int off = 1; off < 256; off <<= 1) {
        int u = (t >= off) ? s[t - off] : 0;
        __syncthreads();
        s[t] += u;
        __syncthreads();
    }
    int incl = s[t];
    if (t == 255) blocksums[b] = incl;
    int run = incl - tsum;
#pragma unroll
    for (int i = 0; i < 4; i++) {
        if (base + i < n) excl[base + i] = run;
        run += v[i];
    }
}

__global__ __launch_bounds__(256) void k_scan_b(const int* __restrict__ blocksums,
                                                int* __restrict__ blockoff, int nb)
{
    __shared__ int s[256];
    int t = threadIdx.x;
    int v = (t < nb) ? blocksums[t] : 0;
    s[t] = v;
    __syncthreads();
    for (int off = 1; off < 256; off <<= 1) {
        int u = (t >= off) ? s[t - off] : 0;
        __syncthreads();
        s[t] += u;
        __syncthreads();
    }
    if (t < nb) blockoff[t] = s[t] - v;
}

__global__ __launch_bounds__(256) void k_scan_c(int* __restrict__ row_start,
                                                int* __restrict__ pos,
                                                const int* __restrict__ blockoff,
                                                int n, int Etot)
{
    int b = blockIdx.x, t = threadIdx.x;
    int base = b * 1024 + t * 4;
    int add = blockoff[b];
#pragma unroll
    for (int i = 0; i < 4; i++) {
        int idx = base + i;
        if (idx < n) {
            int v = row_start[idx] + add;
            row_start[idx] = v;
            pos[idx] = v;
        }
    }
    if (b == 0 && t == 0) row_start[n] = Etot;
}

__global__ __launch_bounds__(256) void k_scatter(const int* __restrict__ erow,
                                                 const int* __restrict__ ecol,
                                                 int* __restrict__ pos,
                                                 int* __restrict__ col_sorted, int E)
{
    int g = blockIdx.x * 256 + threadIdx.x;
    if (g < E) {
        int r = erow[g];
        int idx = atomicAdd(&pos[r], 1);
        col_sorted[idx] = ecol[g];
    }
}

// ---------------- fused segment softmax + SpMM + ELU: one wave per row ------------
__global__ __launch_bounds__(256) void k_gat_row(const float* __restrict__ fts,
                                                 const float* __restrict__ f1,
                                                 const float* __restrict__ f2,
                                                 const int* __restrict__ row_start,
                                                 const int* __restrict__ cols,
                                                 float* __restrict__ out, int Nn)
{
    int wave = blockIdx.x * 4 + (threadIdx.x >> 6);
    int lane = threadIdx.x & 63;
    int r = wave;
    if (r >= Nn) return;

    int s = row_start[r], e = row_start[r + 1];
    int d0 = lane, d1 = lane + 64;
    int h0 = lane >> 5;       // head for dim d0: 0 or 1
    int h1 = h0 + 2;          // head for dim d1: 2 or 3

    if (s == e) {             // empty segment -> agg = 0 -> elu(0) = 0
        out[(size_t)r * 128 + d0] = 0.f;
        out[(size_t)r * 128 + d1] = 0.f;
        return;
    }

    float f1r0 = f1[h0 * Nn + r];
    float f1r1 = f1[h1 * Nn + r];

    float m0 = -INFINITY, m1 = -INFINITY;
    for (int j = s; j < e; j++) {
        int c = cols[j];
        float l0 = f1r0 + f2[h0 * Nn + c]; l0 = fmaxf(l0, ALPHA * l0);
        float l1 = f1r1 + f2[h1 * Nn + c]; l1 = fmaxf(l1, ALPHA * l1);
        m0 = fmaxf(m0, l0);
        m1 = fmaxf(m1, l1);
    }

    float acc0 = 0.f, acc1 = 0.f, ds0 = 0.f, ds1 = 0.f;
    for (int j = s; j < e; j++) {
        int c = cols[j];
        float l0 = f1r0 + f2[h0 * Nn + c]; l0 = fmaxf(l0, ALPHA * l0);
        float l1 = f1r1 + f2[h1 * Nn + c]; l1 = fmaxf(l1, ALPHA * l1);
        float e0 = __expf(l0 - m0);
        float e1 = __expf(l1 - m1);
        ds0 += e0;
        ds1 += e1;
        const float* fr = fts + (size_t)c * 128;
        acc0 = fmaf(e0, fr[d0], acc0);
        acc1 = fmaf(e1, fr[d1], acc1);
    }

    float o0 = acc0 / ds0;
    float o1 = acc1 / ds1;
    o0 = (o0 > 0.f) ? o0 : (__expf(o0) - 1.0f);   // ELU
    o1 = (o1 > 0.f) ? o1 : (__expf(o1) - 1.0f);
    out[(size_t)r * 128 + d0] = o0;
    out[(size_t)r * 128 + d1] = o1;
}

// ---------------------------------------------------------------------------------
extern "C" void kernel_launch(void* const* d_in, const int* in_sizes, int n_in,
                              void* d_out, int out_size, void* d_ws, size_t ws_size,
                              hipStream_t stream)
{
    const float* x   = (const float*)d_in[0];
    const float* W   = (const float*)d_in[1];
    const float* a1  = (const float*)d_in[2];
    const float* b1  = (const float*)d_in[3];
    const float* a2  = (const float*)d_in[4];
    const float* b2  = (const float*)d_in[5];
    const int*   erow = (const int*)d_in[6];
    const int*   ecol = (const int*)d_in[7];
    float* out = (float*)d_out;

    const int N = in_sizes[0] / 256;   // 100000
    const int E = in_sizes[6];         // 1600000

    // workspace carve-up (256B aligned)
    char*  ws  = (char*)d_ws;
    size_t off = 0;
    auto carve = [&](size_t bytes) -> char* {
        char* p = ws + off;
        off += (bytes + 255) & ~(size_t)255;
        return p;
    };
    float* fts       = (float*)carve((size_t)N * 128 * 4);
    float* f1        = (float*)carve((size_t)N * 4 * 4);
    float* f2        = (float*)carve((size_t)N * 4 * 4);
    int*   row_start = (int*)carve(((size_t)N + 1) * 4);
    int*   pos       = (int*)carve((size_t)N * 4);
    int*   counts    = (int*)carve((size_t)N * 4);
    int*   blocksums = (int*)carve(1024);
    int*   blockoff  = (int*)carve(1024);
    int*   col_sorted= (int*)carve((size_t)E * 4);
    (void)ws_size;

    // 1) GEMM
    k_gemm<<<(N + 63) / 64, 256, 0, stream>>>(x, W, fts, N);

    // 2) f1/f2
    k_f12<<<(N * 4 + 255) / 256, 256, 0, stream>>>(fts, a1, b1, a2, b2, f1, f2, N);

    // 3) CSR build
    hipMemsetAsync(counts, 0, (size_t)N * 4, stream);
    k_hist<<<(E + 255) / 256, 256, 0, stream>>>(erow, counts, E);
    int nb = (N + 1023) / 1024;
    k_scan_a<<<nb, 256, 0, stream>>>(counts, row_start, blocksums, N);
    k_scan_b<<<1, 256, 0, stream>>>(blocksums, blockoff, nb);
    k_scan_c<<<nb, 256, 0, stream>>>(row_start, pos, blockoff, N, E);
    k_scatter<<<(E + 255) / 256, 256, 0, stream>>>(erow, ecol, pos, col_sorted, E);

    // 4) fused segment softmax + aggregation + ELU
    k_gat_row<<<(N + 3) / 4, 256, 0, stream>>>(fts, f1, f2, row_start, col_sorted, out, N);
}

// Round 2
// 575.875 us; speedup vs baseline: 1.2825x; 1.2825x over previous
//
#include <hip/hip_runtime.h>
#include <hip/hip_bf16.h>
#include <math.h>

#define ALPHA 0.2f

// ---------------- GEMM: fts[n][h*32+o] = sum_d x[n][d] * W[h][d][o] -------------
__global__ __launch_bounds__(256) void k_gemm(const float* __restrict__ x,
                                              const float* __restrict__ W,
                                              float* __restrict__ fts, int M)
{
    __shared__ float As[16][68];
    __shared__ float Bs[16][128];

    const int m0 = blockIdx.x * 64;
    const int t  = threadIdx.x;
    const int tx = t & 31;
    const int ty = t >> 5;

    float acc[8][4];
#pragma unroll
    for (int i = 0; i < 8; i++)
#pragma unroll
        for (int j = 0; j < 4; j++) acc[i][j] = 0.f;

    for (int k0 = 0; k0 < 256; k0 += 16) {
        {
            int ar = t >> 2, ak = (t & 3) * 4;
            int gr = m0 + ar;
            float4 av = make_float4(0.f, 0.f, 0.f, 0.f);
            if (gr < M) av = *(const float4*)(x + (size_t)gr * 256 + k0 + ak);
            As[ak + 0][ar] = av.x;
            As[ak + 1][ar] = av.y;
            As[ak + 2][ar] = av.z;
            As[ak + 3][ar] = av.w;
        }
#pragma unroll
        for (int p = 0; p < 2; p++) {
            int kb = (t >> 5) + p * 8;
            int c4 = (t & 31) * 4;
            int h = c4 >> 5, o = c4 & 31;
            float4 bv = *(const float4*)(W + h * 8192 + (k0 + kb) * 32 + o);
            *(float4*)&Bs[kb][c4] = bv;
        }
        __syncthreads();
#pragma unroll
        for (int k = 0; k < 16; k++) {
            float4 b4 = *(float4*)&Bs[k][tx * 4];
            float4 aA = *(float4*)&As[k][ty * 8];
            float4 aB = *(float4*)&As[k][ty * 8 + 4];
            float a[8] = {aA.x, aA.y, aA.z, aA.w, aB.x, aB.y, aB.z, aB.w};
#pragma unroll
            for (int i = 0; i < 8; i++) {
                acc[i][0] = fmaf(a[i], b4.x, acc[i][0]);
                acc[i][1] = fmaf(a[i], b4.y, acc[i][1]);
                acc[i][2] = fmaf(a[i], b4.z, acc[i][2]);
                acc[i][3] = fmaf(a[i], b4.w, acc[i][3]);
            }
        }
        __syncthreads();
    }
#pragma unroll
    for (int i = 0; i < 8; i++) {
        int r = m0 + ty * 8 + i;
        if (r < M) {
            float4 v = make_float4(acc[i][0], acc[i][1], acc[i][2], acc[i][3]);
            *(float4*)(fts + (size_t)r * 128 + tx * 4) = v;
        }
    }
}

// ---------------- f1/f2: per (node, head) dot over O=32; INTERLEAVED [n][4] ------
__global__ __launch_bounds__(256) void k_f12(const float* __restrict__ fts,
                                             const float* __restrict__ a1,
                                             const float* __restrict__ b1,
                                             const float* __restrict__ a2,
                                             const float* __restrict__ b2,
                                             float* __restrict__ f1,
                                             float* __restrict__ f2, int Nn)
{
    int g = blockIdx.x * 256 + threadIdx.x;
    int n = g >> 2, h = g & 3;
    if (n >= Nn) return;
    const float* row = fts + (size_t)n * 128 + h * 32;
    const float* A1 = a1 + h * 32;
    const float* A2 = a2 + h * 32;
    float s1 = 0.f, s2 = 0.f;
#pragma unroll
    for (int o = 0; o < 32; o += 4) {
        float4 v  = *(const float4*)(row + o);
        float4 u1 = *(const float4*)(A1 + o);
        float4 u2 = *(const float4*)(A2 + o);
        s1 += v.x * u1.x + v.y * u1.y + v.z * u1.z + v.w * u1.w;
        s2 += v.x * u2.x + v.y * u2.y + v.z * u2.z + v.w * u2.w;
    }
    f1[g] = s1 + b1[h];   // g == n*4 + h
    f2[g] = s2 + b2[h];
}

// ---------------- CSR build --------------------------------------------------------
__global__ __launch_bounds__(256) void k_hist(const int* __restrict__ erow, int* __restrict__ counts, int E)
{
    int g = blockIdx.x * 256 + threadIdx.x;
    if (g < E) atomicAdd(&counts[erow[g]], 1);
}

__global__ __launch_bounds__(256) void k_scan_a(const int* __restrict__ counts,
                                                int* __restrict__ excl,
                                                int* __restrict__ blocksums, int n)
{
    __shared__ int s[256];
    int b = blockIdx.x, t = threadIdx.x;
    int base = b * 1024 + t * 4;
    int v[4];
#pragma unroll
    for (int i = 0; i < 4; i++) v[i] = (base + i < n) ? counts[base + i] : 0;
    int tsum = v[0] + v[1] + v[2] + v[3];
    s[t] = tsum;
    __syncthreads();
    for (int off = 1; off < 256; off <<= 1) {
        int u = (t >= off) ? s[t - off] : 0;
        __syncthreads();
        s[t] += u;
        __syncthreads();
    }
    int incl = s[t];
    if (t == 255) blocksums[b] = incl;
    int run = incl - tsum;
#pragma unroll
    for (int i = 0; i < 4; i++) {
        if (base + i < n) excl[base + i] = run;
        run += v[i];
    }
}

__global__ __launch_bounds__(256) void k_scan_b(const int* __restrict__ blocksums,
                                                int* __restrict__ blockoff, int nb)
{
    __shared__ int s[256];
    int t = threadIdx.x;
    int v = (t < nb) ? blocksums[t] : 0;
    s[t] = v;
    __syncthreads();
    for (int off = 1; off < 256; off <<= 1) {
        int u = (t >= off) ? s[t - off] : 0;
        __syncthreads();
        s[t] += u;
        __syncthreads();
    }
    if (t < nb) blockoff[t] = s[t] - v;
}

__global__ __launch_bounds__(256) void k_scan_c(int* __restrict__ row_start,
                                                int* __restrict__ pos,
                                                const int* __restrict__ blockoff,
                                                int n, int Etot)
{
    int b = blockIdx.x, t = threadIdx.x;
    int base = b * 1024 + t * 4;
    int add = blockoff[b];
#pragma unroll
    for (int i = 0; i < 4; i++) {
        int idx = base + i;
        if (idx < n) {
            int v = row_start[idx] + add;
            row_start[idx] = v;
            pos[idx] = v;
        }
    }
    if (b == 0 && t == 0) row_start[n] = Etot;
}

__global__ __launch_bounds__(256) void k_scatter(const int* __restrict__ erow,
                                                 const int* __restrict__ ecol,
                                                 int* __restrict__ pos,
                                                 int* __restrict__ col_sorted, int E)
{
    int g = blockIdx.x * 256 + threadIdx.x;
    if (g < E) {
        int r = erow[g];
        int idx = atomicAdd(&pos[r], 1);
        col_sorted[idx] = ecol[g];
    }
}

// ---------------- fused segment softmax + SpMM + ELU: one wave per row ------------
// Single pass (no max subtraction: logits bounded ~|8|, exp safe in fp32).
// Phase A: 64 edges in parallel across lanes -> (c, e0..e3) into LDS.
// Phase B: serial broadcast from LDS, coalesced float2 fts gather, unroll 4.
__global__ __launch_bounds__(256) void k_gat_row(const float* __restrict__ fts,
                                                 const float4* __restrict__ f1,
                                                 const float4* __restrict__ f2,
                                                 const int* __restrict__ row_start,
                                                 const int* __restrict__ cols,
                                                 float* __restrict__ out, int Nn)
{
    __shared__ float eL[4][256];   // [wave][edge*4 + head]
    __shared__ int   cL[4][64];    // [wave][edge]

    const int wid  = threadIdx.x >> 6;
    const int lane = threadIdx.x & 63;
    const int r = blockIdx.x * 4 + wid;
    if (r >= Nn) return;

    const int s = row_start[r], e = row_start[r + 1];
    const int hl = lane >> 4;                    // head for dims 2*lane, 2*lane+1

    float2* outp = (float2*)(out + (size_t)r * 128);
    if (s == e) { outp[lane] = make_float2(0.f, 0.f); return; }

    const float4 f1r = f1[r];
    float ds0 = 0.f, ds1 = 0.f, ds2 = 0.f, ds3 = 0.f;
    float acc0 = 0.f, acc1 = 0.f;

    for (int j0 = s; j0 < e; j0 += 64) {
        // ---- Phase A: edge-parallel exp ----
        int j = j0 + lane;
        bool act = (j < e);
        int c = act ? cols[j] : 0;
        float4 f2v = f2[c];
        float l0 = f1r.x + f2v.x; l0 = fmaxf(l0, ALPHA * l0);
        float l1 = f1r.y + f2v.y; l1 = fmaxf(l1, ALPHA * l1);
        float l2 = f1r.z + f2v.z; l2 = fmaxf(l2, ALPHA * l2);
        float l3 = f1r.w + f2v.w; l3 = fmaxf(l3, ALPHA * l3);
        float e0 = act ? __expf(l0) : 0.f;
        float e1 = act ? __expf(l1) : 0.f;
        float e2 = act ? __expf(l2) : 0.f;
        float e3 = act ? __expf(l3) : 0.f;
        ds0 += e0; ds1 += e1; ds2 += e2; ds3 += e3;

        asm volatile("s_waitcnt lgkmcnt(0)" ::: "memory");   // prior reads done before overwrite
        ((float4*)eL[wid])[lane] = make_float4(e0, e1, e2, e3);
        cL[wid][lane] = c;
        asm volatile("s_waitcnt lgkmcnt(0)" ::: "memory");   // writes visible before reads

        // ---- Phase B: serial over chunk, pipelined coalesced gathers ----
        int len = e - j0; if (len > 64) len = 64;
#pragma unroll 4
        for (int jj = 0; jj < len; jj++) {
            float ee = eL[wid][jj * 4 + hl];                 // 16-lane broadcast
            int   cc = cL[wid][jj];                          // full broadcast
            const float2* fp = (const float2*)(fts + (size_t)cc * 128);
            float2 v = fp[lane];                             // coalesced 512B/wave
            acc0 = fmaf(ee, v.x, acc0);
            acc1 = fmaf(ee, v.y, acc1);
        }
    }

    // reduce denominators across lanes (butterfly over 64)
#pragma unroll
    for (int off = 32; off > 0; off >>= 1) {
        ds0 += __shfl_xor(ds0, off, 64);
        ds1 += __shfl_xor(ds1, off, 64);
        ds2 += __shfl_xor(ds2, off, 64);
        ds3 += __shfl_xor(ds3, off, 64);
    }
    float dsel = (hl == 0) ? ds0 : (hl == 1) ? ds1 : (hl == 2) ? ds2 : ds3;

    float o0 = acc0 / dsel;
    float o1 = acc1 / dsel;
    o0 = (o0 > 0.f) ? o0 : (__expf(o0) - 1.0f);
    o1 = (o1 > 0.f) ? o1 : (__expf(o1) - 1.0f);
    outp[lane] = make_float2(o0, o1);
}

// ---------------------------------------------------------------------------------
extern "C" void kernel_launch(void* const* d_in, const int* in_sizes, int n_in,
                              void* d_out, int out_size, void* d_ws, size_t ws_size,
                              hipStream_t stream)
{
    const float* x   = (const float*)d_in[0];
    const float* W   = (const float*)d_in[1];
    const float* a1  = (const float*)d_in[2];
    const float* b1  = (const float*)d_in[3];
    const float* a2  = (const float*)d_in[4];
    const float* b2  = (const float*)d_in[5];
    const int*   erow = (const int*)d_in[6];
    const int*   ecol = (const int*)d_in[7];
    float* out = (float*)d_out;

    const int N = in_sizes[0] / 256;   // 100000
    const int E = in_sizes[6];         // 1600000

    char*  ws  = (char*)d_ws;
    size_t off = 0;
    auto carve = [&](size_t bytes) -> char* {
        char* p = ws + off;
        off += (bytes + 255) & ~(size_t)255;
        return p;
    };
    float* fts       = (float*)carve((size_t)N * 128 * 4);
    float* f1        = (float*)carve((size_t)N * 4 * 4);
    float* f2        = (float*)carve((size_t)N * 4 * 4);
    int*   row_start = (int*)carve(((size_t)N + 1) * 4);
    int*   pos       = (int*)carve((size_t)N * 4);
    int*   counts    = (int*)carve((size_t)N * 4);
    int*   blocksums = (int*)carve(1024);
    int*   blockoff  = (int*)carve(1024);
    int*   col_sorted= (int*)carve((size_t)E * 4);
    (void)ws_size;

    k_gemm<<<(N + 63) / 64, 256, 0, stream>>>(x, W, fts, N);
    k_f12<<<(N * 4 + 255) / 256, 256, 0, stream>>>(fts, a1, b1, a2, b2, f1, f2, N);

    hipMemsetAsync(counts, 0, (size_t)N * 4, stream);
    k_hist<<<(E + 255) / 256, 256, 0, stream>>>(erow, counts, E);
    int nb = (N + 1023) / 1024;
    k_scan_a<<<nb, 256, 0, stream>>>(counts, row_start, blocksums, N);
    k_scan_b<<<1, 256, 0, stream>>>(blocksums, blockoff, nb);
    k_scan_c<<<nb, 256, 0, stream>>>(row_start, pos, blockoff, N, E);
    k_scatter<<<(E + 255) / 256, 256, 0, stream>>>(erow, ecol, pos, col_sorted, E);

    k_gat_row<<<(N + 3) / 4, 256, 0, stream>>>(fts, (const float4*)f1, (const float4*)f2,
                                               row_start, col_sorted, out, N);
}

// Round 3
// 447.964 us; speedup vs baseline: 1.6487x; 1.2855x over previous
//
#include <hip/hip_runtime.h>
#include <hip/hip_bf16.h>
#include <math.h>

#define ALPHA 0.2f
#define PB_EDGES 4096   // edges per partition block

// ---------------- GEMM: fts[n][h*32+o] = sum_d x[n][d] * W[h][d][o] -------------
__global__ __launch_bounds__(256) void k_gemm(const float* __restrict__ x,
                                              const float* __restrict__ W,
                                              float* __restrict__ fts, int M)
{
    __shared__ float As[16][68];
    __shared__ float Bs[16][128];

    const int m0 = blockIdx.x * 64;
    const int t  = threadIdx.x;
    const int tx = t & 31;
    const int ty = t >> 5;

    float acc[8][4];
#pragma unroll
    for (int i = 0; i < 8; i++)
#pragma unroll
        for (int j = 0; j < 4; j++) acc[i][j] = 0.f;

    for (int k0 = 0; k0 < 256; k0 += 16) {
        {
            int ar = t >> 2, ak = (t & 3) * 4;
            int gr = m0 + ar;
            float4 av = make_float4(0.f, 0.f, 0.f, 0.f);
            if (gr < M) av = *(const float4*)(x + (size_t)gr * 256 + k0 + ak);
            As[ak + 0][ar] = av.x;
            As[ak + 1][ar] = av.y;
            As[ak + 2][ar] = av.z;
            As[ak + 3][ar] = av.w;
        }
#pragma unroll
        for (int p = 0; p < 2; p++) {
            int kb = (t >> 5) + p * 8;
            int c4 = (t & 31) * 4;
            int h = c4 >> 5, o = c4 & 31;
            float4 bv = *(const float4*)(W + h * 8192 + (k0 + kb) * 32 + o);
            *(float4*)&Bs[kb][c4] = bv;
        }
        __syncthreads();
#pragma unroll
        for (int k = 0; k < 16; k++) {
            float4 b4 = *(float4*)&Bs[k][tx * 4];
            float4 aA = *(float4*)&As[k][ty * 8];
            float4 aB = *(float4*)&As[k][ty * 8 + 4];
            float a[8] = {aA.x, aA.y, aA.z, aA.w, aB.x, aB.y, aB.z, aB.w};
#pragma unroll
            for (int i = 0; i < 8; i++) {
                acc[i][0] = fmaf(a[i], b4.x, acc[i][0]);
                acc[i][1] = fmaf(a[i], b4.y, acc[i][1]);
                acc[i][2] = fmaf(a[i], b4.z, acc[i][2]);
                acc[i][3] = fmaf(a[i], b4.w, acc[i][3]);
            }
        }
        __syncthreads();
    }
#pragma unroll
    for (int i = 0; i < 8; i++) {
        int r = m0 + ty * 8 + i;
        if (r < M) {
            float4 v = make_float4(acc[i][0], acc[i][1], acc[i][2], acc[i][3]);
            *(float4*)(fts + (size_t)r * 128 + tx * 4) = v;
        }
    }
}

// ---------------- f1/f2: per (node, head) dot over O=32; INTERLEAVED [n][4] ------
__global__ __launch_bounds__(256) void k_f12(const float* __restrict__ fts,
                                             const float* __restrict__ a1,
                                             const float* __restrict__ b1,
                                             const float* __restrict__ a2,
                                             const float* __restrict__ b2,
                                             float* __restrict__ f1,
                                             float* __restrict__ f2, int Nn)
{
    int g = blockIdx.x * 256 + threadIdx.x;
    int n = g >> 2, h = g & 3;
    if (n >= Nn) return;
    const float* row = fts + (size_t)n * 128 + h * 32;
    const float* A1 = a1 + h * 32;
    const float* A2 = a2 + h * 32;
    float s1 = 0.f, s2 = 0.f;
#pragma unroll
    for (int o = 0; o < 32; o += 4) {
        float4 v  = *(const float4*)(row + o);
        float4 u1 = *(const float4*)(A1 + o);
        float4 u2 = *(const float4*)(A2 + o);
        s1 += v.x * u1.x + v.y * u1.y + v.z * u1.z + v.w * u1.w;
        s2 += v.x * u2.x + v.y * u2.y + v.z * u2.z + v.w * u2.w;
    }
    f1[g] = s1 + b1[h];   // g == n*4 + h
    f2[g] = s2 + b2[h];
}

// =============== CSR build via bucketed two-pass sort (NO per-edge global atomics)
// bucket = row >> 8 (256 rows per bucket), NB = ceil(N/256) <= 512

// Pass 1a: per-block LDS histogram of buckets, merged with one atomic per bin
__global__ __launch_bounds__(256) void k_phist(const int* __restrict__ erow,
                                               int* __restrict__ bcnt, int E, int NB)
{
    __shared__ int h[512];
    for (int i = threadIdx.x; i < 512; i += 256) h[i] = 0;
    __syncthreads();
    int b0 = blockIdx.x * PB_EDGES;
    int bend = b0 + PB_EDGES; if (bend > E) bend = E;
    for (int j = b0 + threadIdx.x; j < bend; j += 256)
        atomicAdd(&h[erow[j] >> 8], 1);
    __syncthreads();
    for (int i = threadIdx.x; i < NB; i += 256)
        if (h[i]) atomicAdd(&bcnt[i], h[i]);
}

// Pass 1b: exclusive scan of bucket counts (NB <= 512), one block
__global__ __launch_bounds__(256) void k_scan_buckets(const int* __restrict__ bcnt,
                                                      int* __restrict__ base,
                                                      int* __restrict__ bcursor,
                                                      int NB, int E)
{
    __shared__ int s[256];
    int t = threadIdx.x;
    int i0 = 2 * t, i1 = 2 * t + 1;
    int v0 = (i0 < NB) ? bcnt[i0] : 0;
    int v1 = (i1 < NB) ? bcnt[i1] : 0;
    int tsum = v0 + v1;
    s[t] = tsum;
    __syncthreads();
    for (int off = 1; off < 256; off <<= 1) {
        int u = (t >= off) ? s[t - off] : 0;
        __syncthreads();
        s[t] += u;
        __syncthreads();
    }
    int excl = s[t] - tsum;
    if (i0 < NB) { base[i0] = excl;      bcursor[i0] = excl; }
    if (i1 < NB) { base[i1] = excl + v0; bcursor[i1] = excl + v0; }
    if (t == 0) base[NB] = E;
}

// Pass 1c: partition scatter. Block reserves contiguous space per bin (1 atomic/bin),
// then appends (row,col) records via LDS cursors -> single-writer cache lines.
__global__ __launch_bounds__(256) void k_pscatter(const int* __restrict__ erow,
                                                  const int* __restrict__ ecol,
                                                  int* __restrict__ bcursor,
                                                  uint2* __restrict__ part, int E)
{
    __shared__ int h[512];
    __shared__ int cur[512];
    for (int i = threadIdx.x; i < 512; i += 256) h[i] = 0;
    __syncthreads();
    int b0 = blockIdx.x * PB_EDGES;
    int bend = b0 + PB_EDGES; if (bend > E) bend = E;
    for (int j = b0 + threadIdx.x; j < bend; j += 256)
        atomicAdd(&h[erow[j] >> 8], 1);
    __syncthreads();
    for (int i = threadIdx.x; i < 512; i += 256)
        cur[i] = h[i] ? atomicAdd(&bcursor[i], h[i]) : 0;
    __syncthreads();
    for (int j = b0 + threadIdx.x; j < bend; j += 256) {
        int r = erow[j], c = ecol[j];
        int p = atomicAdd(&cur[r >> 8], 1);
        part[p] = make_uint2((unsigned)r, (unsigned)c);
    }
}

// Pass 2: per-bucket counting sort -> row_start + col_sorted (coalesced/local writes)
__global__ __launch_bounds__(256) void k_bucket(const uint2* __restrict__ part,
                                                const int* __restrict__ base,
                                                int* __restrict__ row_start,
                                                int* __restrict__ col_sorted,
                                                int Nn, int NB, int E)
{
    __shared__ int cnt[256];
    __shared__ int s[256];
    __shared__ int cur[256];
    const int b = blockIdx.x, t = threadIdx.x;
    const int start = base[b], end = base[b + 1];

    cnt[t] = 0;
    __syncthreads();
    for (int j = start + t; j < end; j += 256)
        atomicAdd(&cnt[part[j].x & 255u], 1);
    __syncthreads();
    int v = cnt[t];
    s[t] = v;
    __syncthreads();
    for (int off = 1; off < 256; off <<= 1) {
        int u = (t >= off) ? s[t - off] : 0;
        __syncthreads();
        s[t] += u;
        __syncthreads();
    }
    int excl = s[t] - v;
    int r = b * 256 + t;
    if (r < Nn) row_start[r] = start + excl;
    if (b == 0 && t == 0) row_start[Nn] = E;
    cur[t] = start + excl;
    __syncthreads();
    for (int j = start + t; j < end; j += 256) {
        uint2 rc = part[j];
        int p = atomicAdd(&cur[rc.x & 255u], 1);
        col_sorted[p] = (int)rc.y;
    }
}

// ---------------- fused segment softmax + SpMM + ELU: one wave per row ------------
__global__ __launch_bounds__(256) void k_gat_row(const float* __restrict__ fts,
                                                 const float4* __restrict__ f1,
                                                 const float4* __restrict__ f2,
                                                 const int* __restrict__ row_start,
                                                 const int* __restrict__ cols,
                                                 float* __restrict__ out, int Nn)
{
    __shared__ float eL[4][256];   // [wave][edge*4 + head]
    __shared__ int   cL[4][64];    // [wave][edge]

    const int wid  = threadIdx.x >> 6;
    const int lane = threadIdx.x & 63;
    const int r = blockIdx.x * 4 + wid;
    if (r >= Nn) return;

    const int s = row_start[r], e = row_start[r + 1];
    const int hl = lane >> 4;

    float2* outp = (float2*)(out + (size_t)r * 128);
    if (s == e) { outp[lane] = make_float2(0.f, 0.f); return; }

    const float4 f1r = f1[r];
    float ds0 = 0.f, ds1 = 0.f, ds2 = 0.f, ds3 = 0.f;
    float acc0 = 0.f, acc1 = 0.f;

    for (int j0 = s; j0 < e; j0 += 64) {
        int j = j0 + lane;
        bool act = (j < e);
        int c = act ? cols[j] : 0;
        float4 f2v = f2[c];
        float l0 = f1r.x + f2v.x; l0 = fmaxf(l0, ALPHA * l0);
        float l1 = f1r.y + f2v.y; l1 = fmaxf(l1, ALPHA * l1);
        float l2 = f1r.z + f2v.z; l2 = fmaxf(l2, ALPHA * l2);
        float l3 = f1r.w + f2v.w; l3 = fmaxf(l3, ALPHA * l3);
        float e0 = act ? __expf(l0) : 0.f;
        float e1 = act ? __expf(l1) : 0.f;
        float e2 = act ? __expf(l2) : 0.f;
        float e3 = act ? __expf(l3) : 0.f;
        ds0 += e0; ds1 += e1; ds2 += e2; ds3 += e3;

        asm volatile("s_waitcnt lgkmcnt(0)" ::: "memory");
        ((float4*)eL[wid])[lane] = make_float4(e0, e1, e2, e3);
        cL[wid][lane] = c;
        asm volatile("s_waitcnt lgkmcnt(0)" ::: "memory");

        int len = e - j0; if (len > 64) len = 64;
#pragma unroll 4
        for (int jj = 0; jj < len; jj++) {
            float ee = eL[wid][jj * 4 + hl];
            int   cc = cL[wid][jj];
            const float2* fp = (const float2*)(fts + (size_t)cc * 128);
            float2 vv = fp[lane];
            acc0 = fmaf(ee, vv.x, acc0);
            acc1 = fmaf(ee, vv.y, acc1);
        }
    }

#pragma unroll
    for (int off = 32; off > 0; off >>= 1) {
        ds0 += __shfl_xor(ds0, off, 64);
        ds1 += __shfl_xor(ds1, off, 64);
        ds2 += __shfl_xor(ds2, off, 64);
        ds3 += __shfl_xor(ds3, off, 64);
    }
    float dsel = (hl == 0) ? ds0 : (hl == 1) ? ds1 : (hl == 2) ? ds2 : ds3;

    float o0 = acc0 / dsel;
    float o1 = acc1 / dsel;
    o0 = (o0 > 0.f) ? o0 : (__expf(o0) - 1.0f);
    o1 = (o1 > 0.f) ? o1 : (__expf(o1) - 1.0f);
    outp[lane] = make_float2(o0, o1);
}

// ---------------------------------------------------------------------------------
extern "C" void kernel_launch(void* const* d_in, const int* in_sizes, int n_in,
                              void* d_out, int out_size, void* d_ws, size_t ws_size,
                              hipStream_t stream)
{
    const float* x   = (const float*)d_in[0];
    const float* W   = (const float*)d_in[1];
    const float* a1  = (const float*)d_in[2];
    const float* b1  = (const float*)d_in[3];
    const float* a2  = (const float*)d_in[4];
    const float* b2  = (const float*)d_in[5];
    const int*   erow = (const int*)d_in[6];
    const int*   ecol = (const int*)d_in[7];
    float* out = (float*)d_out;

    const int N = in_sizes[0] / 256;   // 100000
    const int E = in_sizes[6];         // 1600000
    const int NB = (N + 255) >> 8;     // buckets of 256 rows

    char*  ws  = (char*)d_ws;
    size_t off = 0;
    auto carve = [&](size_t bytes) -> char* {
        char* p = ws + off;
        off += (bytes + 255) & ~(size_t)255;
        return p;
    };
    float* fts       = (float*)carve((size_t)N * 128 * 4);
    float* f1        = (float*)carve((size_t)N * 4 * 4);
    float* f2        = (float*)carve((size_t)N * 4 * 4);
    int*   row_start = (int*)carve(((size_t)N + 1) * 4);
    int*   bcnt      = (int*)carve(512 * 4);
    int*   base      = (int*)carve(513 * 4);
    int*   bcursor   = (int*)carve(512 * 4);
    int*   col_sorted= (int*)carve((size_t)E * 4);
    uint2* part      = (uint2*)carve((size_t)E * 8);
    (void)ws_size;

    k_gemm<<<(N + 63) / 64, 256, 0, stream>>>(x, W, fts, N);
    k_f12<<<(N * 4 + 255) / 256, 256, 0, stream>>>(fts, a1, b1, a2, b2, f1, f2, N);

    // CSR build: bucketed two-pass sort
    hipMemsetAsync(bcnt, 0, 512 * 4, stream);
    int npb = (E + PB_EDGES - 1) / PB_EDGES;
    k_phist<<<npb, 256, 0, stream>>>(erow, bcnt, E, NB);
    k_scan_buckets<<<1, 256, 0, stream>>>(bcnt, base, bcursor, NB, E);
    k_pscatter<<<npb, 256, 0, stream>>>(erow, ecol, bcursor, part, E);
    k_bucket<<<NB, 256, 0, stream>>>(part, base, row_start, col_sorted, N, NB, E);

    k_gat_row<<<(N + 3) / 4, 256, 0, stream>>>(fts, (const float4*)f1, (const float4*)f2,
                                               row_start, col_sorted, out, N);
}

// Round 5
// 382.396 us; speedup vs baseline: 1.9314x; 1.1715x over previous
//
#include <hip/hip_runtime.h>
#include <hip/hip_bf16.h>
#include <math.h>

#define ALPHA 0.2f
#define PB_EDGES 4096   // edges per partition block

typedef __attribute__((ext_vector_type(8))) short short8;
typedef __attribute__((ext_vector_type(4))) float floatx4;

__device__ __forceinline__ ushort f2bf(float f) {
    uint u = __float_as_uint(f);
    u += 0x7fff + ((u >> 16) & 1);   // round-to-nearest-even
    return (ushort)(u >> 16);
}

// ---------------- W prep: Wt[c][d] = bf16(W[h][d][o]), c = h*32+o ----------------
__global__ __launch_bounds__(256) void k_wprep(const float* __restrict__ W,
                                               ushort* __restrict__ Wt)
{
    int g = blockIdx.x * 256 + threadIdx.x;   // g = c*256 + d, 128*256 total
    int c = g >> 8, d = g & 255;
    Wt[g] = f2bf(W[(c >> 5) * 8192 + d * 32 + (c & 31)]);
}

// ---------------- MFMA GEMM + fused f1/f2 epilogue -------------------------------
// 64 rows/block, 128 cols, K=256. 4 waves: wave w -> rows 16w..16w+15.
// Outputs: fts2 (bf16 [N][128]), f1/f2 (fp32 interleaved [N][4]).
__global__ __launch_bounds__(256) void k_gemm(const float* __restrict__ x,
                                              const ushort* __restrict__ Wt,
                                              const float* __restrict__ a1v,
                                              const float* __restrict__ b1v,
                                              const float* __restrict__ a2v,
                                              const float* __restrict__ b2v,
                                              ushort* __restrict__ fts2,
                                              float* __restrict__ f1,
                                              float* __restrict__ f2, int M)
{
    // xb[64][264] ushort (row stride 528 B, padded +8 elems); reused as ftsL[64][136]
    __shared__ __align__(16) ushort smem[64 * 264];
    const int t  = threadIdx.x;
    const int m0 = blockIdx.x * 64;

    // stage x -> bf16 LDS (coalesced float4 loads)
#pragma unroll
    for (int i = 0; i < 16; i++) {
        int idx = i * 256 + t;            // float4 index over 64 rows x 64 f4
        int row = idx >> 6, c4 = idx & 63;
        int gr = m0 + row;
        float4 v = make_float4(0.f, 0.f, 0.f, 0.f);
        if (gr < M) v = *(const float4*)(x + (size_t)gr * 256 + c4 * 4);
        ushort4 b;
        b.x = f2bf(v.x); b.y = f2bf(v.y); b.z = f2bf(v.z); b.w = f2bf(v.w);
        *(ushort4*)&smem[row * 264 + c4 * 4] = b;
    }
    __syncthreads();

    const int w = t >> 6, lane = t & 63;
    const int mm = lane & 15, qq = lane >> 4;

    floatx4 acc[8];
#pragma unroll
    for (int ct = 0; ct < 8; ct++) acc[ct] = (floatx4){0.f, 0.f, 0.f, 0.f};

    const ushort* arow = &smem[(16 * w + mm) * 264 + qq * 8];
#pragma unroll
    for (int ks = 0; ks < 8; ks++) {
        short8 a8 = *(const short8*)(arow + ks * 32);
#pragma unroll
        for (int ct = 0; ct < 8; ct++) {
            short8 b8 = *(const short8*)(Wt + (ct * 16 + mm) * 256 + ks * 32 + qq * 8);
            acc[ct] = __builtin_amdgcn_mfma_f32_16x16x32_bf16(a8, b8, acc[ct], 0, 0, 0);
        }
    }

    __syncthreads();                      // all waves done reading xb
    ushort* ftsL = smem;                  // [64][136], stride 272 B (16B-aligned rows)
#pragma unroll
    for (int ct = 0; ct < 8; ct++) {
#pragma unroll
        for (int i = 0; i < 4; i++) {
            int row = 16 * w + qq * 4 + i;          // D: col=lane&15, row=quad*4+reg
            ftsL[row * 136 + ct * 16 + mm] = f2bf(acc[ct][i]);
        }
    }
    __syncthreads();

    // coalesced bf16 fts2 store: thread -> (row = t>>2, 32-col quarter = t&3)
    // 32 ushorts = 64 B = FOUR uint4s (R4 bug: only 2 were copied)
    {
        int row = t >> 2, q4 = t & 3;
        int gr = m0 + row;
        if (gr < M) {
            const uint4* src = (const uint4*)&ftsL[row * 136 + q4 * 32];
            uint4* dst = (uint4*)(fts2 + (size_t)gr * 128 + q4 * 32);
            dst[0] = src[0];
            dst[1] = src[1];
            dst[2] = src[2];
            dst[3] = src[3];
        }
    }
    // fused f1/f2: thread -> (row = t>>2, head = t&3)
    {
        int row = t >> 2, h = t & 3;
        int gr = m0 + row;
        if (gr < M) {
            const ushort* fr = &ftsL[row * 136 + h * 32];
            float s1 = 0.f, s2 = 0.f;
#pragma unroll
            for (int o = 0; o < 32; o++) {
                float v = __uint_as_float((uint)fr[o] << 16);
                s1 = fmaf(v, a1v[h * 32 + o], s1);
                s2 = fmaf(v, a2v[h * 32 + o], s2);
            }
            f1[gr * 4 + h] = s1 + b1v[h];
            f2[gr * 4 + h] = s2 + b2v[h];
        }
    }
}

// =============== CSR build via bucketed two-pass sort (NO per-edge global atomics)
__global__ __launch_bounds__(256) void k_phist(const int* __restrict__ erow,
                                               int* __restrict__ bcnt, int E, int NB)
{
    __shared__ int h[512];
    for (int i = threadIdx.x; i < 512; i += 256) h[i] = 0;
    __syncthreads();
    int b0 = blockIdx.x * PB_EDGES;
    int bend = b0 + PB_EDGES; if (bend > E) bend = E;
    for (int j = b0 + threadIdx.x; j < bend; j += 256)
        atomicAdd(&h[erow[j] >> 8], 1);
    __syncthreads();
    for (int i = threadIdx.x; i < NB; i += 256)
        if (h[i]) atomicAdd(&bcnt[i], h[i]);
}

__global__ __launch_bounds__(256) void k_scan_buckets(const int* __restrict__ bcnt,
                                                      int* __restrict__ base,
                                                      int* __restrict__ bcursor,
                                                      int NB, int E)
{
    __shared__ int s[256];
    int t = threadIdx.x;
    int i0 = 2 * t, i1 = 2 * t + 1;
    int v0 = (i0 < NB) ? bcnt[i0] : 0;
    int v1 = (i1 < NB) ? bcnt[i1] : 0;
    int tsum = v0 + v1;
    s[t] = tsum;
    __syncthreads();
    for (int off = 1; off < 256; off <<= 1) {
        int u = (t >= off) ? s[t - off] : 0;
        __syncthreads();
        s[t] += u;
        __syncthreads();
    }
    int excl = s[t] - tsum;
    if (i0 < NB) { base[i0] = excl;      bcursor[i0] = excl; }
    if (i1 < NB) { base[i1] = excl + v0; bcursor[i1] = excl + v0; }
    if (t == 0) base[NB] = E;
}

// partition scatter: packed record ((r&255)<<24) | c  (c < 2^24)
__global__ __launch_bounds__(256) void k_pscatter(const int* __restrict__ erow,
                                                  const int* __restrict__ ecol,
                                                  int* __restrict__ bcursor,
                                                  uint* __restrict__ part, int E)
{
    __shared__ int h[512];
    __shared__ int cur[512];
    for (int i = threadIdx.x; i < 512; i += 256) h[i] = 0;
    __syncthreads();
    int b0 = blockIdx.x * PB_EDGES;
    int bend = b0 + PB_EDGES; if (bend > E) bend = E;
    for (int j = b0 + threadIdx.x; j < bend; j += 256)
        atomicAdd(&h[erow[j] >> 8], 1);
    __syncthreads();
    for (int i = threadIdx.x; i < 512; i += 256)
        cur[i] = h[i] ? atomicAdd(&bcursor[i], h[i]) : 0;
    __syncthreads();
    for (int j = b0 + threadIdx.x; j < bend; j += 256) {
        int r = erow[j], c = ecol[j];
        int p = atomicAdd(&cur[r >> 8], 1);
        part[p] = ((uint)(r & 255) << 24) | (uint)c;
    }
}

__global__ __launch_bounds__(256) void k_bucket(const uint* __restrict__ part,
                                                const int* __restrict__ base,
                                                int* __restrict__ row_start,
                                                int* __restrict__ col_sorted,
                                                int Nn, int NB, int E)
{
    __shared__ int cnt[256];
    __shared__ int s[256];
    __shared__ int cur[256];
    const int b = blockIdx.x, t = threadIdx.x;
    const int start = base[b], end = base[b + 1];

    cnt[t] = 0;
    __syncthreads();
    for (int j = start + t; j < end; j += 256)
        atomicAdd(&cnt[part[j] >> 24], 1);
    __syncthreads();
    int v = cnt[t];
    s[t] = v;
    __syncthreads();
    for (int off = 1; off < 256; off <<= 1) {
        int u = (t >= off) ? s[t - off] : 0;
        __syncthreads();
        s[t] += u;
        __syncthreads();
    }
    int excl = s[t] - v;
    int r = b * 256 + t;
    if (r < Nn) row_start[r] = start + excl;
    if (b == 0 && t == 0) row_start[Nn] = E;
    cur[t] = start + excl;
    __syncthreads();
    for (int j = start + t; j < end; j += 256) {
        uint rc = part[j];
        int p = atomicAdd(&cur[rc >> 24], 1);
        col_sorted[p] = (int)(rc & 0xffffffu);
    }
}

// ---------------- fused segment softmax + SpMM + ELU: one wave per row ------------
__global__ __launch_bounds__(256) void k_gat_row(const ushort* __restrict__ fts2,
                                                 const float4* __restrict__ f1,
                                                 const float4* __restrict__ f2,
                                                 const int* __restrict__ row_start,
                                                 const int* __restrict__ cols,
                                                 float* __restrict__ out, int Nn)
{
    __shared__ float eL[4][256];
    __shared__ int   cL[4][64];

    const int wid  = threadIdx.x >> 6;
    const int lane = threadIdx.x & 63;
    const int r = blockIdx.x * 4 + wid;
    if (r >= Nn) return;

    const int s = row_start[r], e = row_start[r + 1];
    const int hl = lane >> 4;

    float2* outp = (float2*)(out + (size_t)r * 128);
    if (s == e) { outp[lane] = make_float2(0.f, 0.f); return; }

    const float4 f1r = f1[r];
    float ds0 = 0.f, ds1 = 0.f, ds2 = 0.f, ds3 = 0.f;
    float acc0 = 0.f, acc1 = 0.f;

    for (int j0 = s; j0 < e; j0 += 64) {
        int j = j0 + lane;
        bool act = (j < e);
        int c = act ? cols[j] : 0;
        float4 f2v = f2[c];
        float l0 = f1r.x + f2v.x; l0 = fmaxf(l0, ALPHA * l0);
        float l1 = f1r.y + f2v.y; l1 = fmaxf(l1, ALPHA * l1);
        float l2 = f1r.z + f2v.z; l2 = fmaxf(l2, ALPHA * l2);
        float l3 = f1r.w + f2v.w; l3 = fmaxf(l3, ALPHA * l3);
        float e0 = act ? __expf(l0) : 0.f;
        float e1 = act ? __expf(l1) : 0.f;
        float e2 = act ? __expf(l2) : 0.f;
        float e3 = act ? __expf(l3) : 0.f;
        ds0 += e0; ds1 += e1; ds2 += e2; ds3 += e3;

        asm volatile("s_waitcnt lgkmcnt(0)" ::: "memory");
        ((float4*)eL[wid])[lane] = make_float4(e0, e1, e2, e3);
        cL[wid][lane] = c;
        asm volatile("s_waitcnt lgkmcnt(0)" ::: "memory");

        int len = e - j0; if (len > 64) len = 64;
#pragma unroll 4
        for (int jj = 0; jj < len; jj++) {
            float ee = eL[wid][jj * 4 + hl];
            int   cc = cL[wid][jj];
            const uint* fp = (const uint*)(fts2 + (size_t)cc * 128);
            uint vv = fp[lane];                        // 2 bf16, coalesced 256B/wave
            float vx = __uint_as_float(vv << 16);
            float vy = __uint_as_float(vv & 0xffff0000u);
            acc0 = fmaf(ee, vx, acc0);
            acc1 = fmaf(ee, vy, acc1);
        }
    }

#pragma unroll
    for (int off = 32; off > 0; off >>= 1) {
        ds0 += __shfl_xor(ds0, off, 64);
        ds1 += __shfl_xor(ds1, off, 64);
        ds2 += __shfl_xor(ds2, off, 64);
        ds3 += __shfl_xor(ds3, off, 64);
    }
    float dsel = (hl == 0) ? ds0 : (hl == 1) ? ds1 : (hl == 2) ? ds2 : ds3;

    float o0 = acc0 / dsel;
    float o1 = acc1 / dsel;
    o0 = (o0 > 0.f) ? o0 : (__expf(o0) - 1.0f);
    o1 = (o1 > 0.f) ? o1 : (__expf(o1) - 1.0f);
    outp[lane] = make_float2(o0, o1);
}

// ---------------------------------------------------------------------------------
extern "C" void kernel_launch(void* const* d_in, const int* in_sizes, int n_in,
                              void* d_out, int out_size, void* d_ws, size_t ws_size,
                              hipStream_t stream)
{
    const float* x   = (const float*)d_in[0];
    const float* W   = (const float*)d_in[1];
    const float* a1  = (const float*)d_in[2];
    const float* b1  = (const float*)d_in[3];
    const float* a2  = (const float*)d_in[4];
    const float* b2  = (const float*)d_in[5];
    const int*   erow = (const int*)d_in[6];
    const int*   ecol = (const int*)d_in[7];
    float* out = (float*)d_out;

    const int N = in_sizes[0] / 256;   // 100000
    const int E = in_sizes[6];         // 1600000
    const int NB = (N + 255) >> 8;

    char*  ws  = (char*)d_ws;
    size_t off = 0;
    auto carve = [&](size_t bytes) -> char* {
        char* p = ws + off;
        off += (bytes + 255) & ~(size_t)255;
        return p;
    };
    ushort* fts2      = (ushort*)carve((size_t)N * 128 * 2);
    ushort* Wt        = (ushort*)carve((size_t)128 * 256 * 2);
    float*  f1        = (float*)carve((size_t)N * 4 * 4);
    float*  f2        = (float*)carve((size_t)N * 4 * 4);
    int*    row_start = (int*)carve(((size_t)N + 1) * 4);
    int*    bcnt      = (int*)carve(512 * 4);
    int*    base      = (int*)carve(513 * 4);
    int*    bcursor   = (int*)carve(512 * 4);
    int*    col_sorted= (int*)carve((size_t)E * 4);
    uint*   part      = (uint*)carve((size_t)E * 4);
    (void)ws_size;

    k_wprep<<<128, 256, 0, stream>>>(W, Wt);
    k_gemm<<<(N + 63) / 64, 256, 0, stream>>>(x, Wt, a1, b1, a2, b2, fts2, f1, f2, N);

    hipMemsetAsync(bcnt, 0, 512 * 4, stream);
    int npb = (E + PB_EDGES - 1) / PB_EDGES;
    k_phist<<<npb, 256, 0, stream>>>(erow, bcnt, E, NB);
    k_scan_buckets<<<1, 256, 0, stream>>>(bcnt, base, bcursor, NB, E);
    k_pscatter<<<npb, 256, 0, stream>>>(erow, ecol, bcursor, part, E);
    k_bucket<<<NB, 256, 0, stream>>>(part, base, row_start, col_sorted, N, NB, E);

    k_gat_row<<<(N + 3) / 4, 256, 0, stream>>>(fts2, (const float4*)f1, (const float4*)f2,
                                               row_start, col_sorted, out, N);
}

// Round 6
// 340.742 us; speedup vs baseline: 2.1675x; 1.1222x over previous
//
#include <hip/hip_runtime.h>
#include <hip/hip_bf16.h>
#include <math.h>

#define ALPHA 0.2f
#define PB_EDGES 4096   // edges per partition block

typedef __attribute__((ext_vector_type(8))) short short8;
typedef __attribute__((ext_vector_type(4))) float floatx4;

__device__ __forceinline__ ushort f2bf(float f) {
    uint u = __float_as_uint(f);
    u += 0x7fff + ((u >> 16) & 1);   // round-to-nearest-even
    return (ushort)(u >> 16);
}

__device__ __forceinline__ short8 pack8(float4 lo, float4 hi) {
    short8 r;
    r[0] = (short)f2bf(lo.x); r[1] = (short)f2bf(lo.y);
    r[2] = (short)f2bf(lo.z); r[3] = (short)f2bf(lo.w);
    r[4] = (short)f2bf(hi.x); r[5] = (short)f2bf(hi.y);
    r[6] = (short)f2bf(hi.z); r[7] = (short)f2bf(hi.w);
    return r;
}

// ---------------- W prep: Wt[c][d] = bf16(W[h][d][o]), c = h*32+o ----------------
__global__ __launch_bounds__(256) void k_wprep(const float* __restrict__ W,
                                               ushort* __restrict__ Wt)
{
    int g = blockIdx.x * 256 + threadIdx.x;   // g = c*256 + d, 128*256 total
    int c = g >> 8, d = g & 255;
    Wt[g] = f2bf(W[(c >> 5) * 8192 + d * 32 + (c & 31)]);
}

// ---------------- MFMA GEMM + fused f1/f2 epilogue (v2: ILP restructure) ---------
// 128 rows/block, 128 cols, K=256. 4 waves; wave w owns rows w*32..w*32+31
// (2 row-tiles of 16), all 8 col-tiles.
// LDS: Wt in fragment order [ct][ks][lane] * 16B = 64 KB; reused for epilogue.
__global__ __launch_bounds__(256) void k_gemm(const float* __restrict__ x,
                                              const ushort* __restrict__ Wt,
                                              const float* __restrict__ a1v,
                                              const float* __restrict__ b1v,
                                              const float* __restrict__ a2v,
                                              const float* __restrict__ b2v,
                                              ushort* __restrict__ fts2,
                                              float* __restrict__ f1,
                                              float* __restrict__ f2, int M)
{
    __shared__ __align__(16) ushort smem[32768];   // 64 KB
    const int t  = threadIdx.x;
    const int m0 = blockIdx.x * 128;

    // ---- stage Wt -> LDS in fragment order: frag f = ((ct*8+ks)*64 + lane) ----
    // lane = qq*16+mm; source = Wt[(ct*16+mm)*256 + ks*32 + qq*8], 16B per frag.
#pragma unroll
    for (int i = 0; i < 16; i++) {
        int f = i * 256 + t;
        int lane_ = f & 63, ksct = f >> 6;
        int ks = ksct & 7, ct = ksct >> 3;
        int mm = lane_ & 15, qq = lane_ >> 4;
        *(uint4*)&smem[f * 8] = *(const uint4*)&Wt[(ct * 16 + mm) * 256 + ks * 32 + qq * 8];
    }

    const int w = t >> 6, lane = t & 63;
    const int mm = lane & 15, qq = lane >> 4;

    // ---- prefetch + convert A fragments (2 row-tiles x 8 ks), straight from x ----
    int row0 = m0 + w * 32 + mm;
    int row1 = row0 + 16;
    int r0c = (row0 < M) ? row0 : (M - 1);   // clamp (stores are guarded later)
    int r1c = (row1 < M) ? row1 : (M - 1);
    const float* ar0 = x + (size_t)r0c * 256 + qq * 8;
    const float* ar1 = x + (size_t)r1c * 256 + qq * 8;
    short8 afrag[2][8];
#pragma unroll
    for (int ks = 0; ks < 8; ks++) {
        float4 lo0 = *(const float4*)(ar0 + ks * 32);
        float4 hi0 = *(const float4*)(ar0 + ks * 32 + 4);
        float4 lo1 = *(const float4*)(ar1 + ks * 32);
        float4 hi1 = *(const float4*)(ar1 + ks * 32 + 4);
        afrag[0][ks] = pack8(lo0, hi0);
        afrag[1][ks] = pack8(lo1, hi1);
    }

    floatx4 acc[2][8];
#pragma unroll
    for (int r = 0; r < 2; r++)
#pragma unroll
        for (int ct = 0; ct < 8; ct++) acc[r][ct] = (floatx4){0.f, 0.f, 0.f, 0.f};

    __syncthreads();   // Wt staged

    // ---- main loop: pure ds_read_b128 + MFMA ----
#pragma unroll
    for (int ks = 0; ks < 8; ks++) {
#pragma unroll
        for (int ct = 0; ct < 8; ct++) {
            short8 b8 = *(const short8*)&smem[((ct * 8 + ks) * 64 + lane) * 8];
            acc[0][ct] = __builtin_amdgcn_mfma_f32_16x16x32_bf16(afrag[0][ks], b8, acc[0][ct], 0, 0, 0);
            acc[1][ct] = __builtin_amdgcn_mfma_f32_16x16x32_bf16(afrag[1][ks], b8, acc[1][ct], 0, 0, 0);
        }
    }

    __syncthreads();   // done reading Wt; reuse LDS as ftsL[128][136]
    ushort* ftsL = smem;
#pragma unroll
    for (int r = 0; r < 2; r++)
#pragma unroll
        for (int ct = 0; ct < 8; ct++)
#pragma unroll
            for (int i = 0; i < 4; i++) {
                int rowl = w * 32 + r * 16 + qq * 4 + i;   // D: col=lane&15, row=quad*4+reg
                ftsL[rowl * 136 + ct * 16 + mm] = f2bf(acc[r][ct][i]);
            }
    __syncthreads();

    // coalesced bf16 fts2 store: thread -> (row = t>>1, 64-col half = t&1)
    {
        int rowl = t >> 1, half = t & 1;
        int gr = m0 + rowl;
        if (gr < M) {
            const uint4* src = (const uint4*)&ftsL[rowl * 136 + half * 64];
            uint4* dst = (uint4*)(fts2 + (size_t)gr * 128 + half * 64);
#pragma unroll
            for (int i = 0; i < 8; i++) dst[i] = src[i];
        }
    }
    // fused f1/f2: 512 tasks (row, head), 2 per thread
#pragma unroll
    for (int p = 0; p < 2; p++) {
        int task = p * 256 + t;
        int rowl = task >> 2, h = task & 3;
        int gr = m0 + rowl;
        if (gr < M) {
            const ushort* fr = &ftsL[rowl * 136 + h * 32];
            float s1 = 0.f, s2 = 0.f;
#pragma unroll
            for (int o = 0; o < 32; o++) {
                float v = __uint_as_float((uint)fr[o] << 16);
                s1 = fmaf(v, a1v[h * 32 + o], s1);
                s2 = fmaf(v, a2v[h * 32 + o], s2);
            }
            f1[gr * 4 + h] = s1 + b1v[h];
            f2[gr * 4 + h] = s2 + b2v[h];
        }
    }
}

// =============== CSR build via bucketed two-pass sort (NO per-edge global atomics)
__global__ __launch_bounds__(256) void k_phist(const int* __restrict__ erow,
                                               int* __restrict__ bcnt, int E, int NB)
{
    __shared__ int h[512];
    for (int i = threadIdx.x; i < 512; i += 256) h[i] = 0;
    __syncthreads();
    int b0 = blockIdx.x * PB_EDGES;
    int bend = b0 + PB_EDGES; if (bend > E) bend = E;
    for (int j = b0 + threadIdx.x; j < bend; j += 256)
        atomicAdd(&h[erow[j] >> 8], 1);
    __syncthreads();
    for (int i = threadIdx.x; i < NB; i += 256)
        if (h[i]) atomicAdd(&bcnt[i], h[i]);
}

__global__ __launch_bounds__(256) void k_scan_buckets(const int* __restrict__ bcnt,
                                                      int* __restrict__ base,
                                                      int* __restrict__ bcursor,
                                                      int NB, int E)
{
    __shared__ int s[256];
    int t = threadIdx.x;
    int i0 = 2 * t, i1 = 2 * t + 1;
    int v0 = (i0 < NB) ? bcnt[i0] : 0;
    int v1 = (i1 < NB) ? bcnt[i1] : 0;
    int tsum = v0 + v1;
    s[t] = tsum;
    __syncthreads();
    for (int off = 1; off < 256; off <<= 1) {
        int u = (t >= off) ? s[t - off] : 0;
        __syncthreads();
        s[t] += u;
        __syncthreads();
    }
    int excl = s[t] - tsum;
    if (i0 < NB) { base[i0] = excl;      bcursor[i0] = excl; }
    if (i1 < NB) { base[i1] = excl + v0; bcursor[i1] = excl + v0; }
    if (t == 0) base[NB] = E;
}

// partition scatter: packed record ((r&255)<<24) | c  (c < 2^24)
__global__ __launch_bounds__(256) void k_pscatter(const int* __restrict__ erow,
                                                  const int* __restrict__ ecol,
                                                  int* __restrict__ bcursor,
                                                  uint* __restrict__ part, int E)
{
    __shared__ int h[512];
    __shared__ int cur[512];
    for (int i = threadIdx.x; i < 512; i += 256) h[i] = 0;
    __syncthreads();
    int b0 = blockIdx.x * PB_EDGES;
    int bend = b0 + PB_EDGES; if (bend > E) bend = E;
    for (int j = b0 + threadIdx.x; j < bend; j += 256)
        atomicAdd(&h[erow[j] >> 8], 1);
    __syncthreads();
    for (int i = threadIdx.x; i < 512; i += 256)
        cur[i] = h[i] ? atomicAdd(&bcursor[i], h[i]) : 0;
    __syncthreads();
    for (int j = b0 + threadIdx.x; j < bend; j += 256) {
        int r = erow[j], c = ecol[j];
        int p = atomicAdd(&cur[r >> 8], 1);
        part[p] = ((uint)(r & 255) << 24) | (uint)c;
    }
}

__global__ __launch_bounds__(256) void k_bucket(const uint* __restrict__ part,
                                                const int* __restrict__ base,
                                                int* __restrict__ row_start,
                                                int* __restrict__ col_sorted,
                                                int Nn, int NB, int E)
{
    __shared__ int cnt[256];
    __shared__ int s[256];
    __shared__ int cur[256];
    const int b = blockIdx.x, t = threadIdx.x;
    const int start = base[b], end = base[b + 1];

    cnt[t] = 0;
    __syncthreads();
    for (int j = start + t; j < end; j += 256)
        atomicAdd(&cnt[part[j] >> 24], 1);
    __syncthreads();
    int v = cnt[t];
    s[t] = v;
    __syncthreads();
    for (int off = 1; off < 256; off <<= 1) {
        int u = (t >= off) ? s[t - off] : 0;
        __syncthreads();
        s[t] += u;
        __syncthreads();
    }
    int excl = s[t] - v;
    int r = b * 256 + t;
    if (r < Nn) row_start[r] = start + excl;
    if (b == 0 && t == 0) row_start[Nn] = E;
    cur[t] = start + excl;
    __syncthreads();
    for (int j = start + t; j < end; j += 256) {
        uint rc = part[j];
        int p = atomicAdd(&cur[rc >> 24], 1);
        col_sorted[p] = (int)(rc & 0xffffffu);
    }
}

// ---------------- fused segment softmax + SpMM + ELU: one wave per row ------------
__global__ __launch_bounds__(256) void k_gat_row(const ushort* __restrict__ fts2,
                                                 const float4* __restrict__ f1,
                                                 const float4* __restrict__ f2,
                                                 const int* __restrict__ row_start,
                                                 const int* __restrict__ cols,
                                                 float* __restrict__ out, int Nn)
{
    __shared__ float eL[4][256];
    __shared__ int   cL[4][64];

    const int wid  = threadIdx.x >> 6;
    const int lane = threadIdx.x & 63;
    const int r = blockIdx.x * 4 + wid;
    if (r >= Nn) return;

    const int s = row_start[r], e = row_start[r + 1];
    const int hl = lane >> 4;

    float2* outp = (float2*)(out + (size_t)r * 128);
    if (s == e) { outp[lane] = make_float2(0.f, 0.f); return; }

    const float4 f1r = f1[r];
    float ds0 = 0.f, ds1 = 0.f, ds2 = 0.f, ds3 = 0.f;
    float acc0 = 0.f, acc1 = 0.f;

    for (int j0 = s; j0 < e; j0 += 64) {
        int j = j0 + lane;
        bool act = (j < e);
        int c = act ? cols[j] : 0;
        float4 f2v = f2[c];
        float l0 = f1r.x + f2v.x; l0 = fmaxf(l0, ALPHA * l0);
        float l1 = f1r.y + f2v.y; l1 = fmaxf(l1, ALPHA * l1);
        float l2 = f1r.z + f2v.z; l2 = fmaxf(l2, ALPHA * l2);
        float l3 = f1r.w + f2v.w; l3 = fmaxf(l3, ALPHA * l3);
        float e0 = act ? __expf(l0) : 0.f;
        float e1 = act ? __expf(l1) : 0.f;
        float e2 = act ? __expf(l2) : 0.f;
        float e3 = act ? __expf(l3) : 0.f;
        ds0 += e0; ds1 += e1; ds2 += e2; ds3 += e3;

        asm volatile("s_waitcnt lgkmcnt(0)" ::: "memory");
        ((float4*)eL[wid])[lane] = make_float4(e0, e1, e2, e3);
        cL[wid][lane] = c;
        asm volatile("s_waitcnt lgkmcnt(0)" ::: "memory");

        int len = e - j0; if (len > 64) len = 64;
#pragma unroll 4
        for (int jj = 0; jj < len; jj++) {
            float ee = eL[wid][jj * 4 + hl];
            int   cc = cL[wid][jj];
            const uint* fp = (const uint*)(fts2 + (size_t)cc * 128);
            uint vv = fp[lane];                        // 2 bf16, coalesced 256B/wave
            float vx = __uint_as_float(vv << 16);
            float vy = __uint_as_float(vv & 0xffff0000u);
            acc0 = fmaf(ee, vx, acc0);
            acc1 = fmaf(ee, vy, acc1);
        }
    }

#pragma unroll
    for (int off = 32; off > 0; off >>= 1) {
        ds0 += __shfl_xor(ds0, off, 64);
        ds1 += __shfl_xor(ds1, off, 64);
        ds2 += __shfl_xor(ds2, off, 64);
        ds3 += __shfl_xor(ds3, off, 64);
    }
    float dsel = (hl == 0) ? ds0 : (hl == 1) ? ds1 : (hl == 2) ? ds2 : ds3;

    float o0 = acc0 / dsel;
    float o1 = acc1 / dsel;
    o0 = (o0 > 0.f) ? o0 : (__expf(o0) - 1.0f);
    o1 = (o1 > 0.f) ? o1 : (__expf(o1) - 1.0f);
    outp[lane] = make_float2(o0, o1);
}

// ---------------------------------------------------------------------------------
extern "C" void kernel_launch(void* const* d_in, const int* in_sizes, int n_in,
                              void* d_out, int out_size, void* d_ws, size_t ws_size,
                              hipStream_t stream)
{
    const float* x   = (const float*)d_in[0];
    const float* W   = (const float*)d_in[1];
    const float* a1  = (const float*)d_in[2];
    const float* b1  = (const float*)d_in[3];
    const float* a2  = (const float*)d_in[4];
    const float* b2  = (const float*)d_in[5];
    const int*   erow = (const int*)d_in[6];
    const int*   ecol = (const int*)d_in[7];
    float* out = (float*)d_out;

    const int N = in_sizes[0] / 256;   // 100000
    const int E = in_sizes[6];         // 1600000
    const int NB = (N + 255) >> 8;

    char*  ws  = (char*)d_ws;
    size_t off = 0;
    auto carve = [&](size_t bytes) -> char* {
        char* p = ws + off;
        off += (bytes + 255) & ~(size_t)255;
        return p;
    };
    ushort* fts2      = (ushort*)carve((size_t)N * 128 * 2);
    ushort* Wt        = (ushort*)carve((size_t)128 * 256 * 2);
    float*  f1        = (float*)carve((size_t)N * 4 * 4);
    float*  f2        = (float*)carve((size_t)N * 4 * 4);
    int*    row_start = (int*)carve(((size_t)N + 1) * 4);
    int*    bcnt      = (int*)carve(512 * 4);
    int*    base      = (int*)carve(513 * 4);
    int*    bcursor   = (int*)carve(512 * 4);
    int*    col_sorted= (int*)carve((size_t)E * 4);
    uint*   part      = (uint*)carve((size_t)E * 4);
    (void)ws_size;

    k_wprep<<<128, 256, 0, stream>>>(W, Wt);
    k_gemm<<<(N + 127) / 128, 256, 0, stream>>>(x, Wt, a1, b1, a2, b2, fts2, f1, f2, N);

    hipMemsetAsync(bcnt, 0, 512 * 4, stream);
    int npb = (E + PB_EDGES - 1) / PB_EDGES;
    k_phist<<<npb, 256, 0, stream>>>(erow, bcnt, E, NB);
    k_scan_buckets<<<1, 256, 0, stream>>>(bcnt, base, bcursor, NB, E);
    k_pscatter<<<npb, 256, 0, stream>>>(erow, ecol, bcursor, part, E);
    k_bucket<<<NB, 256, 0, stream>>>(part, base, row_start, col_sorted, N, NB, E);

    k_gat_row<<<(N + 3) / 4, 256, 0, stream>>>(fts2, (const float4*)f1, (const float4*)f2,
                                               row_start, col_sorted, out, N);
}